// Round 2
// baseline (4949.666 us; speedup 1.0000x reference)
//
#include <hip/hip_runtime.h>
#include <cstdint>
#include <cstddef>

typedef __attribute__((ext_vector_type(8))) short bf16x8;
typedef __attribute__((ext_vector_type(4))) float f32x4;

__device__ __forceinline__ unsigned short f2bf(float f) {
    union { float f; unsigned int u; } x; x.f = f;
    unsigned int u = x.u;
    unsigned int r = (u + 0x7fffu + ((u >> 16) & 1u)) >> 16;
    return (unsigned short)r;
}
__device__ __forceinline__ float sigmoidf_(float x) { return 1.0f / (1.0f + __expf(-x)); }
__device__ __forceinline__ float tanhfast_(float x) { return 2.0f / (1.0f + __expf(-2.0f * x)) - 1.0f; }

// ---------------------------------------------------------------------------
// Weight gather: src wi [O][CXW][3][3], wh [O][CHW][3][3]  (fp32)
//             -> dst [O][ky][kx][c] bf16, c = concat(CXW, CHW)
// ---------------------------------------------------------------------------
__global__ void gather_w(const float* __restrict__ wi,
                         const float* __restrict__ wh,
                         unsigned short* __restrict__ dst,
                         int CXW, int CHW, int O)
{
    int C = CXW + CHW;
    int n = O * 9 * C;
    int e = blockIdx.x * 256 + threadIdx.x;
    if (e >= n) return;
    int c = e % C;
    int r = e / C;
    int kx = r % 3; r /= 3;
    int ky = r % 3;
    int o  = r / 3;
    float v = (c < CXW)
        ? wi[((size_t)o * CXW + c) * 9 + ky * 3 + kx]
        : wh[((size_t)o * CHW + (c - CXW)) * 9 + ky * 3 + kx];
    dst[e] = f2bf(v);
}

__global__ void prep_bias(const float* __restrict__ bi0, const float* __restrict__ bh0,
                          const float* __restrict__ bi1, const float* __restrict__ bh1,
                          const float* __restrict__ btp,
                          float* __restrict__ b0, float* __restrict__ b1, float* __restrict__ btf)
{
    int i = blockIdx.x * 256 + threadIdx.x;
    if (i < 512) b0[i] = bi0[i] + bh0[i];
    else if (i < 1024) { int j = i - 512; b1[j] = bi1[j] + bh1[j]; }
    else if (i < 1088) { int j = i - 1024; btf[j] = btp[j]; }
}

// ---------------------------------------------------------------------------
// Transpose [b][C][64][64] (fp32) -> channel-last [b][64][64][C], bf16 or f32.
// grid (64 /*h*/, B), block 256
// ---------------------------------------------------------------------------
template<bool F32OUT>
__global__ void tr_cl(const float* __restrict__ src,
                      void* __restrict__ dst,
                      int C, size_t src_off, size_t src_bstride)
{
    __shared__ float tile[128 * 65];
    const int h = blockIdx.x, b = blockIdx.y;
    const int tid = threadIdx.x;
    const float* s = src + src_off + (size_t)b * src_bstride + h * 64;
    const int n = C * 64;
    for (int i = tid; i < n; i += 256) {
        int c = i >> 6, w = i & 63;
        tile[c * 65 + w] = s[(size_t)c * 4096 + w];
    }
    __syncthreads();
    for (int i = tid; i < n; i += 256) {
        int w = i / C, c = i % C;
        size_t di = ((size_t)((b * 64 + h) * 64 + w)) * C + c;
        float v = tile[c * 65 + w];
        if (F32OUT) ((float*)dst)[di] = v;
        else        ((unsigned short*)dst)[di] = f2bf(v);
    }
}

// ---------------------------------------------------------------------------
// Fused ConvLSTM cell step for one layer.
//   gates = conv3x3(concat(x,h), wcat) + bias; LSTM pointwise; write h(bf16), c(f32)
// x: [B][64][64][CX] bf16 cl, h: [B][64][64][CH] bf16 cl, c: [B][64][64][128] f32 cl
// wcat: [512][3][3][CX+CH] bf16, bias: [512] f32
// grid (4 /*cb*/, 64 /*h*/, 8 /*b*/), block 256 (4 waves)
// Wave (cw=wid&1, nw=wid>>1): channels cb*32+cw*16..+16, w nw*32..+32, all 4 gates.
// ---------------------------------------------------------------------------
template<int CX, int CH>
__global__ __launch_bounds__(256, 3)
void lstm_conv(const unsigned short* __restrict__ xin,
               const unsigned short* __restrict__ hin,
               const float* __restrict__ cin,
               const unsigned short* __restrict__ wcat,
               const float* __restrict__ bias,
               unsigned short* __restrict__ hout,
               float* __restrict__ cout_)
{
    constexpr int C = CX + CH;
    constexpr int LDSW = C + 8;              // +8 bf16 pad -> b128 reads stay 2-way (free)
    __shared__ unsigned short slab[66 * LDSW];

    const int tid = threadIdx.x;
    const int wid = tid >> 6, lane = tid & 63;
    const int quad = lane >> 4, l16 = lane & 15;
    const int cw = wid & 1, nw = wid >> 1;
    const int cb = blockIdx.x;
    const int h  = blockIdx.y;
    const int b  = blockIdx.z;

    f32x4 acc[4][2];
#pragma unroll
    for (int g = 0; g < 4; ++g)
#pragma unroll
        for (int nt = 0; nt < 2; ++nt)
            acc[g][nt] = (f32x4){0.f, 0.f, 0.f, 0.f};

    const int chbase = cb * 32 + cw * 16;
    const unsigned short* wrow[4];
#pragma unroll
    for (int g = 0; g < 4; ++g)
        wrow[g] = wcat + (size_t)(g * 128 + chbase + l16) * (9 * C) + quad * 8;

    const int w0 = nw * 32 + l16;

    for (int ky = 0; ky < 3; ++ky) {
        if (ky) __syncthreads();
        const int r = h + ky - 1;
        // zero pad rows (w'=-1 and w'=64)
        for (int e = tid; e < 2 * LDSW; e += 256) {
            int row = (e < LDSW) ? 0 : 65;
            slab[row * LDSW + (e % LDSW)] = 0;
        }
        constexpr int NCH = 64 * C / 8;
        if ((unsigned)r < 64u) {
            const unsigned short* xrowp = xin + (size_t)(b * 64 + r) * 64 * CX;
            const unsigned short* hrowp = hin + (size_t)(b * 64 + r) * 64 * CH;
            for (int i = tid; i < NCH; i += 256) {
                int e = i * 8, w = e / C, c = e % C;
                const unsigned short* sp = (c < CX) ? (xrowp + w * CX + c)
                                                    : (hrowp + w * CH + (c - CX));
                *(f32x4*)&slab[(w + 1) * LDSW + c] = *(const f32x4*)sp;
            }
        } else {
            for (int i = tid; i < NCH; i += 256) {
                int e = i * 8, w = e / C, c = e % C;
                *(f32x4*)&slab[(w + 1) * LDSW + c] = (f32x4){0.f, 0.f, 0.f, 0.f};
            }
        }
        __syncthreads();

#pragma unroll
        for (int kx = 0; kx < 3; ++kx) {
#pragma unroll
            for (int c0 = 0; c0 < C; c0 += 32) {
                bf16x8 a[4], bb[2];
#pragma unroll
                for (int g = 0; g < 4; ++g)
                    a[g] = *(const bf16x8*)(wrow[g] + (ky * 3 + kx) * C + c0);
#pragma unroll
                for (int nt = 0; nt < 2; ++nt)
                    bb[nt] = *(const bf16x8*)&slab[(w0 + nt * 16 + kx) * LDSW + c0 + quad * 8];
#pragma unroll
                for (int g = 0; g < 4; ++g)
#pragma unroll
                    for (int nt = 0; nt < 2; ++nt)
                        acc[g][nt] = __builtin_amdgcn_mfma_f32_16x16x32_bf16(a[g], bb[nt], acc[g][nt], 0, 0, 0);
            }
        }
    }

    // fused LSTM pointwise epilogue
    const int ch4 = chbase + quad * 4;
    const f32x4 bi  = *(const f32x4*)&bias[0 * 128 + ch4];
    const f32x4 bfg = *(const f32x4*)&bias[1 * 128 + ch4];
    const f32x4 bg  = *(const f32x4*)&bias[2 * 128 + ch4];
    const f32x4 bo  = *(const f32x4*)&bias[3 * 128 + ch4];
#pragma unroll
    for (int nt = 0; nt < 2; ++nt) {
        const int w = w0 + nt * 16;
        const size_t base = ((size_t)((b * 64 + h) * 64 + w)) * 128 + ch4;
        f32x4 cp = *(const f32x4*)&cin[base];
        f32x4 cy;
        union { unsigned short s[4]; uint2 v; } hp;
#pragma unroll
        for (int j = 0; j < 4; ++j) {
            float ig = sigmoidf_(acc[0][nt][j] + bi[j]);
            float fg = sigmoidf_(acc[1][nt][j] + bfg[j]);
            float gg = tanhfast_(acc[2][nt][j] + bg[j]);
            float og = sigmoidf_(acc[3][nt][j] + bo[j]);
            float cyv = fg * cp[j] + ig * gg;
            cy[j] = cyv;
            hp.s[j] = f2bf(og * tanhfast_(cyv));
        }
        *(f32x4*)&cout_[base] = cy;
        *(uint2*)&hout[base] = hp.v;
    }
}

// ---------------------------------------------------------------------------
// Top conv: out[b][t][o][h][w] (fp32, channel-first) = conv3x3(h1, wtop)+btop
// hin [B][64][64][128] bf16 cl, wtopc [64][3][3][128] bf16, grid (64 /*h*/, 8 /*b*/)
// ---------------------------------------------------------------------------
__global__ __launch_bounds__(256, 3)
void top_conv(const unsigned short* __restrict__ hin,
              const unsigned short* __restrict__ wtopc,
              const float* __restrict__ btf,
              float* __restrict__ out, int t)
{
    constexpr int C = 128;
    constexpr int LDSW = C + 8;
    __shared__ unsigned short slab[66 * LDSW];

    const int tid = threadIdx.x;
    const int wid = tid >> 6, lane = tid & 63;
    const int quad = lane >> 4, l16 = lane & 15;
    const int mw = wid & 1, nw = wid >> 1;
    const int h = blockIdx.x, b = blockIdx.y;

    f32x4 acc[2][2];
#pragma unroll
    for (int mt = 0; mt < 2; ++mt)
#pragma unroll
        for (int nt = 0; nt < 2; ++nt)
            acc[mt][nt] = (f32x4){0.f, 0.f, 0.f, 0.f};

    const unsigned short* wrow[2];
#pragma unroll
    for (int mt = 0; mt < 2; ++mt)
        wrow[mt] = wtopc + (size_t)(mw * 32 + mt * 16 + l16) * (9 * C) + quad * 8;

    const int w0 = nw * 32 + l16;

    for (int ky = 0; ky < 3; ++ky) {
        if (ky) __syncthreads();
        const int r = h + ky - 1;
        for (int e = tid; e < 2 * LDSW; e += 256) {
            int row = (e < LDSW) ? 0 : 65;
            slab[row * LDSW + (e % LDSW)] = 0;
        }
        constexpr int NCH = 64 * C / 8;
        if ((unsigned)r < 64u) {
            const unsigned short* rowp = hin + (size_t)(b * 64 + r) * 64 * C;
            for (int i = tid; i < NCH; i += 256) {
                int e = i * 8, w = e / C, c = e % C;
                *(f32x4*)&slab[(w + 1) * LDSW + c] = *(const f32x4*)(rowp + e);
            }
        } else {
            for (int i = tid; i < NCH; i += 256) {
                int e = i * 8, w = e / C, c = e % C;
                *(f32x4*)&slab[(w + 1) * LDSW + c] = (f32x4){0.f, 0.f, 0.f, 0.f};
            }
        }
        __syncthreads();

#pragma unroll
        for (int kx = 0; kx < 3; ++kx) {
#pragma unroll
            for (int c0 = 0; c0 < C; c0 += 32) {
                bf16x8 a[2], bb[2];
#pragma unroll
                for (int mt = 0; mt < 2; ++mt)
                    a[mt] = *(const bf16x8*)(wrow[mt] + (ky * 3 + kx) * C + c0);
#pragma unroll
                for (int nt = 0; nt < 2; ++nt)
                    bb[nt] = *(const bf16x8*)&slab[(w0 + nt * 16 + kx) * LDSW + c0 + quad * 8];
#pragma unroll
                for (int mt = 0; mt < 2; ++mt)
#pragma unroll
                    for (int nt = 0; nt < 2; ++nt)
                        acc[mt][nt] = __builtin_amdgcn_mfma_f32_16x16x32_bf16(a[mt], bb[nt], acc[mt][nt], 0, 0, 0);
            }
        }
    }

#pragma unroll
    for (int mt = 0; mt < 2; ++mt)
#pragma unroll
        for (int nt = 0; nt < 2; ++nt) {
            const int w = w0 + nt * 16;
#pragma unroll
            for (int j = 0; j < 4; ++j) {
                int o = mw * 32 + mt * 16 + quad * 4 + j;
                float v = acc[mt][nt][j] + btf[o];
                out[(((size_t)(b * 10 + t) * 64 + o) * 64 + h) * 64 + w] = v;
            }
        }
}

// ---------------------------------------------------------------------------
extern "C" void kernel_launch(void* const* d_in, const int* in_sizes, int n_in,
                              void* d_out, int out_size, void* d_ws, size_t ws_size,
                              hipStream_t stream)
{
    const float* target = (const float*)d_in[0];
    const float* h0i = (const float*)d_in[1];
    const float* c0i = (const float*)d_in[2];
    const float* h1i = (const float*)d_in[3];
    const float* c1i = (const float*)d_in[4];
    const float* wi0 = (const float*)d_in[5];
    const float* bi0 = (const float*)d_in[6];
    const float* wh0 = (const float*)d_in[7];
    const float* bh0 = (const float*)d_in[8];
    const float* wi1 = (const float*)d_in[9];
    const float* bi1 = (const float*)d_in[10];
    const float* wh1 = (const float*)d_in[11];
    const float* bh1 = (const float*)d_in[12];
    const float* wtp = (const float*)d_in[13];
    const float* btp = (const float*)d_in[14];
    float* out = (float*)d_out;

    char* ws = (char*)d_ws;
    size_t off = 0;
    auto alloc = [&](size_t bytes) {
        char* p = ws + off;
        off += (bytes + 255) & ~(size_t)255;
        return (void*)p;
    };
    unsigned short* xcur  = (unsigned short*)alloc((size_t)8 * 64 * 64 * 64 * 2);
    unsigned short* h0A   = (unsigned short*)alloc((size_t)8 * 64 * 64 * 128 * 2);
    unsigned short* h0B   = (unsigned short*)alloc((size_t)8 * 64 * 64 * 128 * 2);
    unsigned short* h1A   = (unsigned short*)alloc((size_t)8 * 64 * 64 * 128 * 2);
    unsigned short* h1B   = (unsigned short*)alloc((size_t)8 * 64 * 64 * 128 * 2);
    float*          c0f   = (float*)alloc((size_t)8 * 64 * 64 * 128 * 4);
    float*          c1f   = (float*)alloc((size_t)8 * 64 * 64 * 128 * 4);
    unsigned short* wcat0 = (unsigned short*)alloc((size_t)512 * 9 * 192 * 2);
    unsigned short* wcat1 = (unsigned short*)alloc((size_t)512 * 9 * 256 * 2);
    unsigned short* wtc   = (unsigned short*)alloc((size_t)64 * 9 * 128 * 2);
    float*          b0s   = (float*)alloc(512 * 4);
    float*          b1s   = (float*)alloc(512 * 4);
    float*          btf   = (float*)alloc(64 * 4);

    gather_w<<<(512 * 9 * 192 + 255) / 256, 256, 0, stream>>>(wi0, wh0, wcat0, 64, 128, 512);
    gather_w<<<(512 * 9 * 256 + 255) / 256, 256, 0, stream>>>(wi1, wh1, wcat1, 128, 128, 512);
    gather_w<<<(64 * 9 * 128 + 255) / 256, 256, 0, stream>>>(wtp, wtp, wtc, 128, 0, 64);
    prep_bias<<<5, 256, 0, stream>>>(bi0, bh0, bi1, bh1, btp, b0s, b1s, btf);

    dim3 trg(64, 8);
    tr_cl<false><<<trg, 256, 0, stream>>>(h0i, h0A, 128, 0, (size_t)128 * 4096);
    tr_cl<false><<<trg, 256, 0, stream>>>(h1i, h1A, 128, 0, (size_t)128 * 4096);
    tr_cl<true ><<<trg, 256, 0, stream>>>(c0i, c0f, 128, 0, (size_t)128 * 4096);
    tr_cl<true ><<<trg, 256, 0, stream>>>(c1i, c1f, 128, 0, (size_t)128 * 4096);

    // out[:, 0] from initial top hidden state
    top_conv<<<dim3(64, 8), 256, 0, stream>>>(h1A, wtc, btf, out, 0);

    unsigned short* h0p[2] = { h0A, h0B };
    unsigned short* h1p[2] = { h1A, h1B };
    for (int t = 0; t < 9; ++t) {
        int p = t & 1;
        tr_cl<false><<<trg, 256, 0, stream>>>(target, xcur, 64,
                                              (size_t)t * 262144, (size_t)2621440);
        lstm_conv<64, 128><<<dim3(4, 64, 8), 256, 0, stream>>>(
            xcur, h0p[p], c0f, wcat0, b0s, h0p[1 - p], c0f);
        lstm_conv<128, 128><<<dim3(4, 64, 8), 256, 0, stream>>>(
            h0p[1 - p], h1p[p], c1f, wcat1, b1s, h1p[1 - p], c1f);
        top_conv<<<dim3(64, 8), 256, 0, stream>>>(h1p[1 - p], wtc, btf, out, t + 1);
    }
}

// Round 3
// 2764.199 us; speedup vs baseline: 1.7906x; 1.7906x over previous
//
#include <hip/hip_runtime.h>
#include <cstdint>
#include <cstddef>

typedef __attribute__((ext_vector_type(8))) short bf16x8;
typedef __attribute__((ext_vector_type(4))) float f32x4;

__device__ __forceinline__ unsigned short f2bf(float f) {
    union { float f; unsigned int u; } x; x.f = f;
    unsigned int u = x.u;
    unsigned int r = (u + 0x7fffu + ((u >> 16) & 1u)) >> 16;
    return (unsigned short)r;
}
__device__ __forceinline__ float sigmoidf_(float x) { return 1.0f / (1.0f + __expf(-x)); }
__device__ __forceinline__ float tanhfast_(float x) { return 2.0f / (1.0f + __expf(-2.0f * x)) - 1.0f; }

// ---------------------------------------------------------------------------
// Weight gather: wi [O][CXW][3][3], wh [O][CHW][3][3] (fp32) -> [O][ky][kx][c] bf16
// ---------------------------------------------------------------------------
__global__ void gather_w(const float* __restrict__ wi,
                         const float* __restrict__ wh,
                         unsigned short* __restrict__ dst,
                         int CXW, int CHW, int O)
{
    int C = CXW + CHW;
    int n = O * 9 * C;
    int e = blockIdx.x * 256 + threadIdx.x;
    if (e >= n) return;
    int c = e % C;
    int r = e / C;
    int kx = r % 3; r /= 3;
    int ky = r % 3;
    int o  = r / 3;
    float v = (c < CXW)
        ? wi[((size_t)o * CXW + c) * 9 + ky * 3 + kx]
        : wh[((size_t)o * CHW + (c - CXW)) * 9 + ky * 3 + kx];
    dst[e] = f2bf(v);
}

__global__ void prep_bias(const float* __restrict__ bi0, const float* __restrict__ bh0,
                          const float* __restrict__ bi1, const float* __restrict__ bh1,
                          const float* __restrict__ btp,
                          float* __restrict__ b0, float* __restrict__ b1, float* __restrict__ btf)
{
    int i = blockIdx.x * 256 + threadIdx.x;
    if (i < 512) b0[i] = bi0[i] + bh0[i];
    else if (i < 1024) { int j = i - 512; b1[j] = bi1[j] + bh1[j]; }
    else if (i < 1088) { int j = i - 1024; btf[j] = btp[j]; }
}

// ---------------------------------------------------------------------------
// Transpose [b][C][64][64] (fp32) -> channel-last [b][64][64][C], bf16 or f32.
// grid (64 h, B, Z), block 256.  z selects a slice: src += z*src_zstride,
// dst element offset += z*dst_zstride.
// ---------------------------------------------------------------------------
template<bool F32OUT>
__global__ void tr_cl(const float* __restrict__ src,
                      void* __restrict__ dst,
                      int C, size_t src_off, size_t src_bstride,
                      size_t src_zstride, size_t dst_zstride)
{
    __shared__ float tile[128 * 65];
    const int h = blockIdx.x, b = blockIdx.y, z = blockIdx.z;
    const int tid = threadIdx.x;
    const float* s = src + src_off + (size_t)z * src_zstride + (size_t)b * src_bstride + h * 64;
    const int n = C * 64;
    for (int i = tid; i < n; i += 256) {
        int c = i >> 6, w = i & 63;
        tile[c * 65 + w] = s[(size_t)c * 4096 + w];
    }
    __syncthreads();
    for (int i = tid; i < n; i += 256) {
        int w = i / C, c = i % C;
        size_t di = (size_t)z * dst_zstride + ((size_t)((b * 64 + h) * 64 + w)) * C + c;
        float v = tile[c * 65 + w];
        if (F32OUT) ((float*)dst)[di] = v;
        else        ((unsigned short*)dst)[di] = f2bf(v);
    }
}

// ---------------------------------------------------------------------------
// Fused ConvLSTM cell step, v3: one block = one (b,h) row, full M=512.
// 512 threads = 8 waves; wave ct owns out-channels ct*16..+16 for ALL 4 gates
// and ALL 64 w.  acc[4 gates][4 n-tiles] = 64 VGPRs.
// Register-prefetch staging: next row's global loads issued before MFMA phase.
// ---------------------------------------------------------------------------
template<int CX, int CH>
__global__ __launch_bounds__(512, 4)   // VGPR<=128 -> 2 blocks/CU
void lstm_conv(const unsigned short* __restrict__ xin,
               const unsigned short* __restrict__ hin,
               const float* __restrict__ cin,
               const unsigned short* __restrict__ wcat,
               const float* __restrict__ bias,
               unsigned short* __restrict__ hout,
               float* __restrict__ cout_)
{
    constexpr int C = CX + CH;
    constexpr int LDSW = C + 8;            // row stride 528/400 B == 4 banks mod 32 -> 2-way (free)
    __shared__ unsigned short slab[66 * LDSW];
    constexpr int NS = (64 * C) / (8 * 512);   // 16B chunks per thread per row

    const int tid = threadIdx.x;
    const int wid = tid >> 6, lane = tid & 63;
    const int quad = lane >> 4, l16 = lane & 15;
    const int ct = wid;
    const int bx = blockIdx.x;
    const int h = ((bx & 7) << 3) | (bx >> 3);   // XCD swizzle: contiguous h-band per XCD
    const int b = blockIdx.y;

    f32x4 acc[4][4];
#pragma unroll
    for (int g = 0; g < 4; ++g)
#pragma unroll
        for (int nt = 0; nt < 4; ++nt)
            acc[g][nt] = (f32x4){0.f, 0.f, 0.f, 0.f};

    const unsigned short* wr[4];
#pragma unroll
    for (int g = 0; g < 4; ++g)
        wr[g] = wcat + (size_t)(g * 128 + ct * 16 + l16) * (9 * C) + quad * 8;

    // per-thread staging chunk coords
    int sw[NS], sc[NS], sl[NS];
#pragma unroll
    for (int s = 0; s < NS; ++s) {
        int e = (tid + s * 512) * 8;
        sw[s] = e / C; sc[s] = e % C;
        sl[s] = (sw[s] + 1) * LDSW + sc[s];
    }

    f32x4 st[NS];
    auto load_row = [&](int r) {
        if ((unsigned)r < 64u) {
            const unsigned short* xr = xin + ((size_t)b * 64 + r) * (64 * CX);
            const unsigned short* hr = hin + ((size_t)b * 64 + r) * (64 * CH);
#pragma unroll
            for (int s = 0; s < NS; ++s) {
                const unsigned short* sp = (sc[s] < CX) ? (xr + sw[s] * CX + sc[s])
                                                        : (hr + sw[s] * CH + (sc[s] - CX));
                st[s] = *(const f32x4*)sp;
            }
        } else {
#pragma unroll
            for (int s = 0; s < NS; ++s) st[s] = (f32x4){0.f, 0.f, 0.f, 0.f};
        }
    };
    auto store_row = [&]() {
#pragma unroll
        for (int s = 0; s < NS; ++s) *(f32x4*)&slab[sl[s]] = st[s];
    };

    // prologue: zero pad rows (w'=-1, w'=64), stage row h-1
    load_row(h - 1);
    for (int e = tid; e < 2 * LDSW; e += 512)
        slab[(e < LDSW) ? e : (65 * LDSW + (e - LDSW))] = 0;
    store_row();
    __syncthreads();

#pragma unroll
    for (int ky = 0; ky < 3; ++ky) {
        if (ky < 2) load_row(h + ky);     // prefetch next row (latency hidden by MFMA below)

#pragma unroll
        for (int kx = 0; kx < 3; ++kx) {
#pragma unroll
            for (int c0 = 0; c0 < C; c0 += 32) {
                bf16x8 a[4];
#pragma unroll
                for (int g = 0; g < 4; ++g)
                    a[g] = *(const bf16x8*)(wr[g] + (ky * 3 + kx) * C + c0);
#pragma unroll
                for (int nt = 0; nt < 4; ++nt) {
                    bf16x8 bb = *(const bf16x8*)&slab[(l16 + nt * 16 + kx) * LDSW + c0 + quad * 8];
#pragma unroll
                    for (int g = 0; g < 4; ++g)
                        acc[g][nt] = __builtin_amdgcn_mfma_f32_16x16x32_bf16(a[g], bb, acc[g][nt], 0, 0, 0);
                }
            }
        }

        if (ky < 2) {
            __syncthreads();              // all waves done reading slab
            store_row();
            __syncthreads();              // new row visible
        }
    }

    // fused LSTM pointwise epilogue (wave-local: all 4 gates present)
    const int ch4 = ct * 16 + quad * 4;
    const f32x4 bi  = *(const f32x4*)&bias[0 * 128 + ch4];
    const f32x4 bfg = *(const f32x4*)&bias[1 * 128 + ch4];
    const f32x4 bg  = *(const f32x4*)&bias[2 * 128 + ch4];
    const f32x4 bo  = *(const f32x4*)&bias[3 * 128 + ch4];
#pragma unroll
    for (int nt = 0; nt < 4; ++nt) {
        const int w = l16 + nt * 16;
        const size_t base = ((size_t)((b * 64 + h) * 64 + w)) * 128 + ch4;
        f32x4 cp = *(const f32x4*)&cin[base];
        f32x4 cy;
        union { unsigned short s[4]; uint2 v; } hp;
#pragma unroll
        for (int j = 0; j < 4; ++j) {
            float ig = sigmoidf_(acc[0][nt][j] + bi[j]);
            float fg = sigmoidf_(acc[1][nt][j] + bfg[j]);
            float gg = tanhfast_(acc[2][nt][j] + bg[j]);
            float og = sigmoidf_(acc[3][nt][j] + bo[j]);
            float cyv = fg * cp[j] + ig * gg;
            cy[j] = cyv;
            hp.s[j] = f2bf(og * tanhfast_(cyv));
        }
        *(f32x4*)&cout_[base] = cy;
        *(uint2*)&hout[base] = hp.v;
    }
}

// ---------------------------------------------------------------------------
// Top conv v3: out[b][t][o][h][w] (fp32 cf) = conv3x3(h1, wtop)+btop
// 512 threads = 8 waves: ct=wid&3 (16 out-ch), nh=wid>>2 (w half), acc[2].
// ---------------------------------------------------------------------------
__global__ __launch_bounds__(512, 4)
void top_conv(const unsigned short* __restrict__ hin,
              const unsigned short* __restrict__ wtopc,
              const float* __restrict__ btf,
              float* __restrict__ out, int t)
{
    constexpr int C = 128;
    constexpr int LDSW = C + 8;
    __shared__ unsigned short slab[66 * LDSW];
    constexpr int NS = (64 * C) / (8 * 512);   // 2

    const int tid = threadIdx.x;
    const int wid = tid >> 6, lane = tid & 63;
    const int quad = lane >> 4, l16 = lane & 15;
    const int ct = wid & 3, nh = wid >> 2;
    const int bx = blockIdx.x;
    const int h = ((bx & 7) << 3) | (bx >> 3);
    const int b = blockIdx.y;

    f32x4 acc[2];
    acc[0] = (f32x4){0.f, 0.f, 0.f, 0.f};
    acc[1] = (f32x4){0.f, 0.f, 0.f, 0.f};

    const unsigned short* wr = wtopc + (size_t)(ct * 16 + l16) * (9 * C) + quad * 8;
    const int w0 = nh * 32 + l16;

    int sw[NS], sl[NS];
#pragma unroll
    for (int s = 0; s < NS; ++s) {
        int e = (tid + s * 512) * 8;
        sw[s] = e >> 7;
        sl[s] = (sw[s] + 1) * LDSW + (e & 127);
    }
    f32x4 st[NS];
    auto load_row = [&](int r) {
        if ((unsigned)r < 64u) {
            const unsigned short* rp = hin + ((size_t)b * 64 + r) * (64 * C);
#pragma unroll
            for (int s = 0; s < NS; ++s) st[s] = *(const f32x4*)(rp + (tid + s * 512) * 8);
        } else {
#pragma unroll
            for (int s = 0; s < NS; ++s) st[s] = (f32x4){0.f, 0.f, 0.f, 0.f};
        }
    };
    auto store_row = [&]() {
#pragma unroll
        for (int s = 0; s < NS; ++s) *(f32x4*)&slab[sl[s]] = st[s];
    };

    load_row(h - 1);
    for (int e = tid; e < 2 * LDSW; e += 512)
        slab[(e < LDSW) ? e : (65 * LDSW + (e - LDSW))] = 0;
    store_row();
    __syncthreads();

#pragma unroll
    for (int ky = 0; ky < 3; ++ky) {
        if (ky < 2) load_row(h + ky);
#pragma unroll
        for (int kx = 0; kx < 3; ++kx) {
#pragma unroll
            for (int c0 = 0; c0 < C; c0 += 32) {
                bf16x8 a = *(const bf16x8*)(wr + (ky * 3 + kx) * C + c0);
#pragma unroll
                for (int nt = 0; nt < 2; ++nt) {
                    bf16x8 bb = *(const bf16x8*)&slab[(w0 + nt * 16 + kx) * LDSW + c0 + quad * 8];
                    acc[nt] = __builtin_amdgcn_mfma_f32_16x16x32_bf16(a, bb, acc[nt], 0, 0, 0);
                }
            }
        }
        if (ky < 2) {
            __syncthreads();
            store_row();
            __syncthreads();
        }
    }

#pragma unroll
    for (int nt = 0; nt < 2; ++nt) {
        const int w = w0 + nt * 16;
#pragma unroll
        for (int j = 0; j < 4; ++j) {
            int o = ct * 16 + quad * 4 + j;
            out[(((size_t)(b * 10 + t) * 64 + o) * 64 + h) * 64 + w] = acc[nt][j] + btf[o];
        }
    }
}

// ---------------------------------------------------------------------------
extern "C" void kernel_launch(void* const* d_in, const int* in_sizes, int n_in,
                              void* d_out, int out_size, void* d_ws, size_t ws_size,
                              hipStream_t stream)
{
    const float* target = (const float*)d_in[0];
    const float* h0i = (const float*)d_in[1];
    const float* c0i = (const float*)d_in[2];
    const float* h1i = (const float*)d_in[3];
    const float* c1i = (const float*)d_in[4];
    const float* wi0 = (const float*)d_in[5];
    const float* bi0 = (const float*)d_in[6];
    const float* wh0 = (const float*)d_in[7];
    const float* bh0 = (const float*)d_in[8];
    const float* wi1 = (const float*)d_in[9];
    const float* bi1 = (const float*)d_in[10];
    const float* wh1 = (const float*)d_in[11];
    const float* bh1 = (const float*)d_in[12];
    const float* wtp = (const float*)d_in[13];
    const float* btp = (const float*)d_in[14];
    float* out = (float*)d_out;

    char* ws = (char*)d_ws;
    size_t off = 0;
    auto alloc = [&](size_t bytes) {
        char* p = ws + off;
        off += (bytes + 255) & ~(size_t)255;
        return (void*)p;
    };
    const size_t XSTEP = (size_t)8 * 64 * 64 * 64;          // elements per timestep slice
    unsigned short* xall  = (unsigned short*)alloc(XSTEP * 9 * 2);
    unsigned short* h0A   = (unsigned short*)alloc((size_t)8 * 64 * 64 * 128 * 2);
    unsigned short* h0B   = (unsigned short*)alloc((size_t)8 * 64 * 64 * 128 * 2);
    unsigned short* h1A   = (unsigned short*)alloc((size_t)8 * 64 * 64 * 128 * 2);
    unsigned short* h1B   = (unsigned short*)alloc((size_t)8 * 64 * 64 * 128 * 2);
    float*          c0f   = (float*)alloc((size_t)8 * 64 * 64 * 128 * 4);
    float*          c1f   = (float*)alloc((size_t)8 * 64 * 64 * 128 * 4);
    unsigned short* wcat0 = (unsigned short*)alloc((size_t)512 * 9 * 192 * 2);
    unsigned short* wcat1 = (unsigned short*)alloc((size_t)512 * 9 * 256 * 2);
    unsigned short* wtc   = (unsigned short*)alloc((size_t)64 * 9 * 128 * 2);
    float*          b0s   = (float*)alloc(512 * 4);
    float*          b1s   = (float*)alloc(512 * 4);
    float*          btf   = (float*)alloc(64 * 4);

    gather_w<<<(512 * 9 * 192 + 255) / 256, 256, 0, stream>>>(wi0, wh0, wcat0, 64, 128, 512);
    gather_w<<<(512 * 9 * 256 + 255) / 256, 256, 0, stream>>>(wi1, wh1, wcat1, 128, 128, 512);
    gather_w<<<(64 * 9 * 128 + 255) / 256, 256, 0, stream>>>(wtp, wtp, wtc, 128, 0, 64);
    prep_bias<<<5, 256, 0, stream>>>(bi0, bh0, bi1, bh1, btp, b0s, b1s, btf);

    // initial states -> channel-last
    tr_cl<false><<<dim3(64, 8, 1), 256, 0, stream>>>(h0i, h0A, 128, 0, (size_t)128 * 4096, 0, 0);
    tr_cl<false><<<dim3(64, 8, 1), 256, 0, stream>>>(h1i, h1A, 128, 0, (size_t)128 * 4096, 0, 0);
    tr_cl<true ><<<dim3(64, 8, 1), 256, 0, stream>>>(c0i, c0f, 128, 0, (size_t)128 * 4096, 0, 0);
    tr_cl<true ><<<dim3(64, 8, 1), 256, 0, stream>>>(c1i, c1f, 128, 0, (size_t)128 * 4096, 0, 0);
    // all 9 input timesteps -> channel-last, one dispatch
    tr_cl<false><<<dim3(64, 8, 9), 256, 0, stream>>>(target, xall, 64,
                                                     0, (size_t)10 * 64 * 4096,
                                                     (size_t)64 * 4096, XSTEP);

    top_conv<<<dim3(64, 8), 512, 0, stream>>>(h1A, wtc, btf, out, 0);

    unsigned short* h0p[2] = { h0A, h0B };
    unsigned short* h1p[2] = { h1A, h1B };
    for (int t = 0; t < 9; ++t) {
        int p = t & 1;
        lstm_conv<64, 128><<<dim3(64, 8), 512, 0, stream>>>(
            xall + (size_t)t * XSTEP, h0p[p], c0f, wcat0, b0s, h0p[1 - p], c0f);
        lstm_conv<128, 128><<<dim3(64, 8), 512, 0, stream>>>(
            h0p[1 - p], h1p[p], c1f, wcat1, b1s, h1p[1 - p], c1f);
        top_conv<<<dim3(64, 8), 512, 0, stream>>>(h1p[1 - p], wtc, btf, out, t + 1);
    }
}